// Round 5
// baseline (183.820 us; speedup 1.0000x reference)
//
#include <hip/hip_runtime.h>
#include <hip/hip_bf16.h>
#include <stdint.h>

#define M_DIM 8192
#define N_DIM 4096
#define K_DIM 4096

#define BM 256
#define BN 256
#define BK 64                 // bytes of K per LDS tile = one mfma_i32_16x16x64_i8 K
#define NT (K_DIM / BK)       // 64 K-tiles
#define DEPTH 4               // circular LDS pipeline depth

typedef int v4i __attribute__((ext_vector_type(4)));

#define AS1C(p) ((const __attribute__((address_space(1))) void*)(p))
#define AS3(p)  ((__attribute__((address_space(3))) void*)(p))

// ---------------------------------------------------------------------------
// Fused pack pass: int32 (int8-range) -> int8 for BOTH operands, one launch.
// ---------------------------------------------------------------------------
__device__ __forceinline__ int pack4(int a, int b, int c, int d) {
  return (a & 0xff) | ((b & 0xff) << 8) | ((c & 0xff) << 16) | (d << 24);
}

__global__ void pack_both_kernel(const int* __restrict__ x, const int* __restrict__ w,
                                 char* __restrict__ A8, char* __restrict__ B8,
                                 int nA, int nTot) {
  int idx = blockIdx.x * blockDim.x + threadIdx.x;
  int stride = gridDim.x * blockDim.x;
  for (int i = idx; i < nTot; i += stride) {
    const int4* pin;
    int4* pout;
    if (i < nA) {
      pin  = (const int4*)x + 4 * (size_t)i;
      pout = (int4*)A8 + i;
    } else {
      int j = i - nA;
      pin  = (const int4*)w + 4 * (size_t)j;
      pout = (int4*)B8 + j;
    }
    int4 v0 = pin[0];
    int4 v1 = pin[1];
    int4 v2 = pin[2];
    int4 v3 = pin[3];
    int4 o;
    o.x = pack4(v0.x, v0.y, v0.z, v0.w);
    o.y = pack4(v1.x, v1.y, v1.z, v1.w);
    o.z = pack4(v2.x, v2.y, v2.z, v2.w);
    o.w = pack4(v3.x, v3.y, v3.z, v3.w);
    *pout = o;
  }
}

// ---------------------------------------------------------------------------
// int8 GEMM: 256x256 tile, 8 waves (2Mx4N, per-wave 128x64), BK=64B,
// mfma_i32_16x16x64_i8, 4-deep LDS circular pipeline, counted vmcnt,
// CROSS-PHASE REGISTER PREFETCH so ds_reads overlap MFMA clusters:
//
//   per tile t: s_waitcnt vmcnt(4) lgkmcnt(0); s_barrier
//               STAGE(t+3)
//               read af_hi(t)            [4 ds]  \ overlaps
//               MFMA-lo(t)  (16 MFMA)            / each other
//               read bf,af_lo(t+1)       [8 ds]  \ overlaps
//               MFMA-hi(t)  (16 MFMA)            /
//
// Safety: vmcnt(4)+barrier => all waves' stages of tiles <= t+1 complete
// (4 outstanding = tile t+2 only), so reading buf[(t+1)&3] is legal.
// lgkmcnt(0) at phase top => all reads of buf[(t-1)&3] drained in every
// wave before STAGE(t+3) overwrites it.  Peak live frags = 16 v4i.
// ---------------------------------------------------------------------------
__global__ __launch_bounds__(512, 2) void gemm_i8_kernel(
    const char* __restrict__ A8, const char* __restrict__ B8,
    const int* __restrict__ bias, const float* __restrict__ alpha_p,
    const float* __restrict__ beta_p, int* __restrict__ out) {
  __shared__ alignas(16) char lds[DEPTH][BM * BK + BN * BK];  // 4 x 32 KiB

  const int tid  = threadIdx.x;
  const int lane = tid & 63;
  const int wave = tid >> 6;

  // XCD-aware bijective swizzle: 512 blocks, 64 consecutive per XCD.
  const int orig = blockIdx.x;
  const int swz  = (orig & 7) * (512 / 8) + (orig >> 3);
  const int bm   = (swz >> 4) * BM;  // 32 row-tiles
  const int bn   = (swz & 15) * BN;  // 16 col-tiles

  // Staging geometry: per operand tile 16 KB = 2 rounds x 512 thr x 16 B.
  // Pre-swizzled global chunk g = p ^ ((row>>1)&3) (both-sides swizzle).
  int aoff[2], boff[2], ldsoff[2];
#pragma unroll
  for (int i = 0; i < 2; ++i) {
    int linear = i * 8192 + tid * 16;
    int row = linear >> 6;           // 64 B rows
    int p   = (linear >> 4) & 3;
    int g   = p ^ ((row >> 1) & 3);
    ldsoff[i] = i * 8192 + wave * 1024;       // wave-uniform LDS base
    aoff[i] = (bm + row) * K_DIM + g * 16;
    boff[i] = (bn + row) * K_DIM + g * 16;
  }

#define STAGE_AB(t)                                                                 \
  do {                                                                              \
    const char* ab_ = A8 + (t) * BK;                                                \
    const char* bb_ = B8 + (t) * BK;                                                \
    char* base_ = &lds[(t) & (DEPTH - 1)][0];                                       \
    _Pragma("unroll") for (int i_ = 0; i_ < 2; ++i_) {                              \
      __builtin_amdgcn_global_load_lds(AS1C(ab_ + aoff[i_]),                        \
                                       AS3(base_ + ldsoff[i_]), 16, 0, 0);          \
      __builtin_amdgcn_global_load_lds(AS1C(bb_ + boff[i_]),                        \
                                       AS3(base_ + 16384 + ldsoff[i_]), 16, 0, 0);  \
    }                                                                               \
  } while (0)

  v4i acc[8][4];
#pragma unroll
  for (int i = 0; i < 8; ++i)
#pragma unroll
    for (int j = 0; j < 4; ++j) acc[i][j] = (v4i){0, 0, 0, 0};

  const int wr = wave >> 2;         // 0..1 (M half: 128 rows)
  const int wc = wave & 3;          // 0..3 (N quarter: 64 cols)
  const int frow = lane & 15;
  const int fchunk = lane >> 4;
  // swizzle XOR depends only on frow (rows differ by multiples of 16) -> lane-const
  const int swzoff = ((fchunk ^ ((frow >> 1) & 3)) << 4);

  // Two fragment sets (static selection via unroll-by-2) + shared af_hi.
  v4i bf0[4], aflo0[4], bf1[4], aflo1[4], afhi[4];

#define READ_LO(S, t)                                                               \
  do {                                                                              \
    const char* base_ = &lds[(t) & (DEPTH - 1)][0];                                 \
    _Pragma("unroll") for (int nj = 0; nj < 4; ++nj)                                \
      bf##S[nj] = *(const v4i*)(base_ + 16384 + (wc * 64 + nj * 16 + frow) * 64 +   \
                                swzoff);                                            \
    _Pragma("unroll") for (int mi = 0; mi < 4; ++mi)                                \
      aflo##S[mi] = *(const v4i*)(base_ + (wr * 128 + mi * 16 + frow) * 64 +        \
                                  swzoff);                                          \
  } while (0)

#define READ_HI(t)                                                                  \
  do {                                                                              \
    const char* base_ = &lds[(t) & (DEPTH - 1)][0];                                 \
    _Pragma("unroll") for (int mi = 0; mi < 4; ++mi)                                \
      afhi[mi] = *(const v4i*)(base_ + (wr * 128 + (mi + 4) * 16 + frow) * 64 +     \
                               swzoff);                                             \
  } while (0)

#define MFMA_LO(S)                                                                  \
  do {                                                                              \
    __builtin_amdgcn_s_setprio(1);                                                  \
    _Pragma("unroll") for (int mi = 0; mi < 4; ++mi)                                \
      _Pragma("unroll") for (int nj = 0; nj < 4; ++nj)                              \
        acc[mi][nj] = __builtin_amdgcn_mfma_i32_16x16x64_i8(aflo##S[mi], bf##S[nj], \
                                                            acc[mi][nj], 0, 0, 0); \
    __builtin_amdgcn_s_setprio(0);                                                  \
  } while (0)

#define MFMA_HI(S)                                                                  \
  do {                                                                              \
    __builtin_amdgcn_s_setprio(1);                                                  \
    _Pragma("unroll") for (int mi = 0; mi < 4; ++mi)                                \
      _Pragma("unroll") for (int nj = 0; nj < 4; ++nj)                              \
        acc[mi + 4][nj] = __builtin_amdgcn_mfma_i32_16x16x64_i8(afhi[mi], bf##S[nj],\
                                                                acc[mi + 4][nj],   \
                                                                0, 0, 0);          \
    __builtin_amdgcn_s_setprio(0);                                                  \
  } while (0)

#define ITER(t, C, N, DO_STAGE)                                                     \
  do {                                                                              \
    asm volatile("s_waitcnt vmcnt(4) lgkmcnt(0)" ::: "memory");                     \
    __builtin_amdgcn_s_barrier();                                                   \
    if (DO_STAGE) STAGE_AB((t) + 3);                                                \
    READ_HI(t);                                                                     \
    __builtin_amdgcn_sched_barrier(0);                                              \
    MFMA_LO(C);                                                                     \
    READ_LO(N, (t) + 1);                                                            \
    __builtin_amdgcn_sched_barrier(0);                                              \
    MFMA_HI(C);                                                                     \
  } while (0)

  // Prologue: fill 3 pipeline stages; load tile-0 lo-frags into set 0.
  STAGE_AB(0);
  STAGE_AB(1);
  STAGE_AB(2);
  asm volatile("s_waitcnt vmcnt(8)" ::: "memory");
  __builtin_amdgcn_s_barrier();
  READ_LO(0, 0);

  for (int t = 0; t < NT - 2; t += 2) {        // t = 0..60, 31 pairs
    ITER(t, 0, 1, true);                       // stage t+3 (<= 63 always)
    ITER(t + 1, 1, 0, (t + 4) < NT);
  }
  // Peeled tile NT-2 = 62 (lo-frags in set 0 from loop's last READ_LO).
  asm volatile("s_waitcnt vmcnt(0) lgkmcnt(0)" ::: "memory");
  __builtin_amdgcn_s_barrier();
  READ_HI(NT - 2);
  __builtin_amdgcn_sched_barrier(0);
  MFMA_LO(0);
  READ_LO(1, NT - 1);
  __builtin_amdgcn_sched_barrier(0);
  MFMA_HI(0);
  // Peeled tile NT-1 = 63 (lo-frags in set 1).
  READ_HI(NT - 1);
  __builtin_amdgcn_sched_barrier(0);
  MFMA_LO(1);
  MFMA_HI(1);

  // Epilogue: D = rint(alpha*acc + beta*bias[n]).
  // C/D layout (16x16): col = lane&15, row = (lane>>4)*4 + reg.
  const float alpha = *alpha_p;
  const float beta  = *beta_p;
  const int col0 = bn + wc * 64 + frow;
  float bb4[4];
#pragma unroll
  for (int nj = 0; nj < 4; ++nj) bb4[nj] = beta * (float)bias[col0 + nj * 16];

  const int rbase = bm + wr * 128 + (lane >> 4) * 4;
#pragma unroll
  for (int mi = 0; mi < 8; ++mi) {
#pragma unroll
    for (int r = 0; r < 4; ++r) {
      size_t rowoff = (size_t)(rbase + mi * 16 + r) * N_DIM;
#pragma unroll
      for (int nj = 0; nj < 4; ++nj) {
        out[rowoff + col0 + nj * 16] =
            (int)rintf(fmaf(alpha, (float)acc[mi][nj][r], bb4[nj]));
      }
    }
  }
#undef STAGE_AB
#undef READ_LO
#undef READ_HI
#undef MFMA_LO
#undef MFMA_HI
#undef ITER
}

// ---------------------------------------------------------------------------
// Safety fallback if ws is too small for the packed operands (slow but right).
// ---------------------------------------------------------------------------
__global__ void naive_kernel(const int* __restrict__ x, const int* __restrict__ w,
                             const int* __restrict__ bias,
                             const float* __restrict__ alpha_p,
                             const float* __restrict__ beta_p,
                             int* __restrict__ out) {
  size_t idx = (size_t)blockIdx.x * 256 + threadIdx.x;
  int m = (int)(idx / N_DIM);
  int n = (int)(idx % N_DIM);
  const int4* xr = (const int4*)(x + (size_t)m * K_DIM);
  const int4* wr = (const int4*)(w + (size_t)n * K_DIM);
  int acc = 0;
  for (int k = 0; k < K_DIM / 4; ++k) {
    int4 a = xr[k];
    int4 b = wr[k];
    acc += a.x * b.x + a.y * b.y + a.z * b.z + a.w * b.w;
  }
  out[idx] = (int)rintf(fmaf(*alpha_p, (float)acc, (*beta_p) * (float)bias[n]));
}

extern "C" void kernel_launch(void* const* d_in, const int* in_sizes, int n_in,
                              void* d_out, int out_size, void* d_ws, size_t ws_size,
                              hipStream_t stream) {
  const int*   x     = (const int*)d_in[0];
  const int*   w     = (const int*)d_in[1];
  const int*   bias  = (const int*)d_in[2];
  const float* alpha = (const float*)d_in[3];
  const float* beta  = (const float*)d_in[4];
  int* out = (int*)d_out;

  const size_t a8_bytes = (size_t)M_DIM * K_DIM;  // 32 MiB
  const size_t b8_bytes = (size_t)N_DIM * K_DIM;  // 16 MiB

  if (ws_size >= a8_bytes + b8_bytes) {
    char* A8 = (char*)d_ws;
    char* B8 = A8 + a8_bytes;
    const int nA = (int)(a8_bytes / 16);
    const int nTot = (int)((a8_bytes + b8_bytes) / 16);
    pack_both_kernel<<<2048, 256, 0, stream>>>(x, w, A8, B8, nA, nTot);
    const int nblk = (M_DIM / BM) * (N_DIM / BN);  // 32*16 = 512
    gemm_i8_kernel<<<nblk, 512, 0, stream>>>(A8, B8, bias, alpha, beta, out);
  } else {
    naive_kernel<<<(M_DIM * (size_t)N_DIM) / 256, 256, 0, stream>>>(x, w, bias, alpha, beta, out);
  }
}